// Round 9
// baseline (627.085 us; speedup 1.0000x reference)
//
#include <hip/hip_runtime.h>

#define NN 32768
#define NE 131072
#define NB 512
#define SL 1000

using bf16x8 = __attribute__((ext_vector_type(8))) short;
using f32x4  = __attribute__((ext_vector_type(4))) float;

static __device__ __forceinline__ unsigned short f2b(float f) {
  union { float f; unsigned u; } x; x.f = f;
  unsigned r = x.u + 0x7fffu + ((x.u >> 16) & 1u);  // RNE
  return (unsigned short)(r >> 16);
}

// ---------------- degree (int) ----------------
__global__ void k_degi(const int* __restrict__ dst, int* __restrict__ degi, int E) {
  int e = blockIdx.x * 256 + threadIdx.x;
  if (e < E) atomicAdd(&degi[dst[e]], 1);
}

// ---------------- CSR scan (1 block) + dis = rsqrt(1+deg) fused ----------------
__global__ void k_scan(const int* __restrict__ degi, int* __restrict__ base,
                       int* __restrict__ cursor, float* __restrict__ dis) {
  __shared__ int part[1024];
  int tid = threadIdx.x;
  int v[32];
  int s = 0;
  int lo = tid * 32;
#pragma unroll
  for (int i = 0; i < 32; ++i) { v[i] = degi[lo + i]; s += v[i]; }
  part[tid] = s;
  __syncthreads();
  for (int off = 1; off < 1024; off <<= 1) {
    int val = (tid >= off) ? part[tid - off] : 0;
    __syncthreads();
    part[tid] += val;
    __syncthreads();
  }
  int run = (tid > 0) ? part[tid - 1] : 0;
#pragma unroll
  for (int i = 0; i < 32; ++i) {
    base[lo + i] = run;
    cursor[lo + i] = run;
    dis[lo + i] = rsqrtf(1.0f + (float)v[i]);
    run += v[i];
  }
  if (tid == 1023) base[NN] = run;
}

__global__ void k_fill(const int* __restrict__ src, const int* __restrict__ dst,
                       int* __restrict__ cursor, unsigned short* __restrict__ csr_src, int E) {
  int e = blockIdx.x * 256 + threadIdx.x;
  if (e < E) {
    int d = dst[e];
    int pos = atomicAdd(&cursor[d], 1);
    csr_src[pos] = (unsigned short)src[e];  // node ids < 32768 fit in u16
  }
}

// ---------------- GCN aggregate (gather, incl. self-loop term), float4/thread ----------------
template<int C>
__global__ void k_gather4(const float* __restrict__ xw, const float* __restrict__ dis,
                          const int* __restrict__ base, const unsigned short* __restrict__ csr_src,
                          float* __restrict__ agg, int N) {
  constexpr int TPN = C / 4;
  int t = blockIdx.x * 256 + threadIdx.x;
  int n = t / TPN;
  if (n >= N) return;
  int c = (t % TPN) * 4;
  float dn = dis[n];
  float s2 = dn * dn;
  float4 acc = *(const float4*)&xw[(long)n * C + c];
  acc.x *= s2; acc.y *= s2; acc.z *= s2; acc.w *= s2;
  int b0 = base[n], b1 = base[n + 1];
  for (int j = b0; j < b1; ++j) {
    int s = csr_src[j];
    float coef = dis[s] * dn;
    float4 v = *(const float4*)&xw[(long)s * C + c];
    acc.x += v.x * coef; acc.y += v.y * coef;
    acc.z += v.z * coef; acc.w += v.w * coef;
  }
  *(float4*)&agg[(long)n * C + c] = acc;
}

// ---------------- weight prep: fp32 [co][ci][k] -> bf16 [k][co][ci]; emb -> bf16 ----------------
__global__ void k_prep(const float* __restrict__ emb, const float* __restrict__ ck1,
                       const float* __restrict__ ck2, const float* __restrict__ ck3,
                       unsigned short* __restrict__ emb_bf, unsigned short* __restrict__ wt1,
                       unsigned short* __restrict__ wt2, unsigned short* __restrict__ wt3) {
  int idx = blockIdx.x * 256 + threadIdx.x;
  if (idx < 3328) {                       // emb 26x128
    emb_bf[idx] = f2b(emb[idx]);
  } else if (idx < 3328 + 16384) {        // wt1[k<4][co<32][ci<128]
    int i = idx - 3328;
    int kt = i >> 12, co = (i >> 7) & 31, ci = i & 127;
    wt1[i] = f2b(ck1[co * 512 + ci * 4 + kt]);
  } else if (idx < 3328 + 16384 + 12288) { // wt2[k<6][co<64][ci<32]
    int i = idx - 3328 - 16384;
    int kt = i >> 11, co = (i >> 5) & 63, ci = i & 31;
    wt2[i] = f2b(ck2[co * 192 + ci * 6 + kt]);
  } else if (idx < 3328 + 16384 + 12288 + 49152) { // wt3[k<8][co<96][ci<64]
    int i = idx - 3328 - 16384 - 12288;
    int kt = i / 6144, co = (i >> 6) % 96, ci = i & 63;
    wt3[i] = f2b(ck3[co * 512 + ci * 8 + kt]);
  }
}

// ---------------- simple dense layer (layer 1, K=5) ----------------
template<int C_OUT, int K, bool RELU, bool BIAS>
__launch_bounds__(256)
__global__ void k_fc(const float* __restrict__ in, const float* __restrict__ W,
                     const float* __restrict__ bias, float* __restrict__ out, int N) {
  constexpr int CO4 = C_OUT / 4;
  int gid = blockIdx.x * 256 + threadIdx.x;
  int n = gid / CO4;
  if (n >= N) return;
  int co = (gid - n * CO4) * 4;
  const float* row = in + (long)n * K;
  float ax = 0.f, ay = 0.f, az = 0.f, aw = 0.f;
  if (BIAS) {
    float4 b4 = *(const float4*)&bias[co];
    ax = b4.x; ay = b4.y; az = b4.z; aw = b4.w;
  }
#pragma unroll 4
  for (int ci = 0; ci < K; ++ci) {
    float a = row[ci];
    float4 w = *(const float4*)&W[(long)ci * C_OUT + co];
    ax += a * w.x; ay += a * w.y; az += a * w.z; aw += a * w.w;
  }
  if (RELU) {
    ax = fmaxf(ax, 0.f); ay = fmaxf(ay, 0.f); az = fmaxf(az, 0.f); aw = fmaxf(aw, 0.f);
  }
  float4 o; o.x = ax; o.y = ay; o.z = az; o.w = aw;
  *(float4*)&out[(long)n * C_OUT + co] = o;
}

// ---------------- register-tiled dense layer: TN nodes x 4 co per thread ----------------
// BNIN: input element a -> fmaxf(a*bn[ci]+bn[K+ci], 0) on load (bitwise == old bnrelu pass).
template<int C_OUT, int K, int TN, bool RELU, bool BIAS, bool BNIN>
__launch_bounds__(256)
__global__ void k_fc4(const float* __restrict__ in, const float* __restrict__ W,
                      const float* __restrict__ bias, const float* __restrict__ bn,
                      float* __restrict__ out, int N) {
  constexpr int CO4 = C_OUT / 4;
  constexpr int GPB = 256 / CO4;
  int g = blockIdx.x * GPB + threadIdx.x / CO4;
  long n0 = (long)g * TN;
  if (n0 >= N) return;
  int co = (threadIdx.x % CO4) * 4;
  float4 acc[TN];
  float4 b4 = {0.f, 0.f, 0.f, 0.f};
  if (BIAS) b4 = *(const float4*)&bias[co];
#pragma unroll
  for (int t = 0; t < TN; ++t) acc[t] = b4;
  for (int ci = 0; ci < K; ci += 4) {
    float4 w0 = *(const float4*)&W[(long)(ci + 0) * C_OUT + co];
    float4 w1 = *(const float4*)&W[(long)(ci + 1) * C_OUT + co];
    float4 w2 = *(const float4*)&W[(long)(ci + 2) * C_OUT + co];
    float4 w3 = *(const float4*)&W[(long)(ci + 3) * C_OUT + co];
    float4 sc4, sh4;
    if (BNIN) {
      sc4 = *(const float4*)&bn[ci];
      sh4 = *(const float4*)&bn[K + ci];
    }
#pragma unroll
    for (int t = 0; t < TN; ++t) {
      float4 a = *(const float4*)&in[(n0 + t) * K + ci];
      if (BNIN) {
        a.x = fmaxf(a.x * sc4.x + sh4.x, 0.f);
        a.y = fmaxf(a.y * sc4.y + sh4.y, 0.f);
        a.z = fmaxf(a.z * sc4.z + sh4.z, 0.f);
        a.w = fmaxf(a.w * sc4.w + sh4.w, 0.f);
      }
      acc[t].x += a.x * w0.x; acc[t].y += a.x * w0.y; acc[t].z += a.x * w0.z; acc[t].w += a.x * w0.w;
      acc[t].x += a.y * w1.x; acc[t].y += a.y * w1.y; acc[t].z += a.y * w1.z; acc[t].w += a.y * w1.w;
      acc[t].x += a.z * w2.x; acc[t].y += a.z * w2.y; acc[t].z += a.z * w2.z; acc[t].w += a.z * w2.w;
      acc[t].x += a.w * w3.x; acc[t].y += a.w * w3.y; acc[t].z += a.w * w3.z; acc[t].w += a.w * w3.w;
    }
  }
#pragma unroll
  for (int t = 0; t < TN; ++t) {
    float4 o = acc[t];
    if (RELU) {
      o.x = fmaxf(o.x, 0.f); o.y = fmaxf(o.y, 0.f);
      o.z = fmaxf(o.z, 0.f); o.w = fmaxf(o.w, 0.f);
    }
    *(float4*)&out[(n0 + t) * C_OUT + co] = o;
  }
}

// ---------------- batchnorm stats + (last block) finalize scale/shift ----------------
template<int C>
__global__ void k_bnstats(const float* __restrict__ h, float* __restrict__ stats,
                          const float* __restrict__ g, const float* __restrict__ bt,
                          int* __restrict__ counter, int N) {
  constexpr int RPB = 256 / C;
  int c = threadIdx.x % C;
  int r = threadIdx.x / C;
  float s = 0.f, ss = 0.f;
  for (int n = blockIdx.x * RPB + r; n < N; n += gridDim.x * RPB) {
    float v = h[(long)n * C + c];
    s += v; ss += v * v;
  }
  __shared__ float ls[256], lss[256];
  __shared__ int s_last;
  ls[threadIdx.x] = s; lss[threadIdx.x] = ss;
  __syncthreads();
  if (threadIdx.x < C) {
    float st = 0.f, sst = 0.f;
#pragma unroll
    for (int r2 = 0; r2 < RPB; ++r2) { st += ls[c + r2 * C]; sst += lss[c + r2 * C]; }
    atomicAdd(&stats[c], st);
    atomicAdd(&stats[C + c], sst);
  }
  __syncthreads();
  __threadfence();
  if (threadIdx.x == 0) s_last = (atomicAdd(counter, 1) == (int)gridDim.x - 1);
  __syncthreads();
  if (s_last && threadIdx.x < C) {
    __threadfence();
    // coherent cross-XCD read of the fully-accumulated sums
    float sum = atomicAdd(&stats[c], 0.0f);
    float ssq = atomicAdd(&stats[C + c], 0.0f);
    float m = sum / (float)N;
    float v = ssq / (float)N - m * m;
    float sc = g[c] * rsqrtf(v + 1e-5f);
    stats[c] = sc;
    stats[C + c] = bt[c] - m * sc;
  }
}

// ---------------- fused BN+relu+mean-pool over sorted batch ranges ----------------
__global__ void k_pool2bn(const float* __restrict__ agg, const float* __restrict__ stats,
                          const int* __restrict__ batch, float* __restrict__ cbuf) {
  int b = blockIdx.x;
  __shared__ int s_lo, s_hi;
  if (threadIdx.x == 0) {
    int lo = 0, hi = NN;
    while (lo < hi) { int m = (lo + hi) >> 1; if (batch[m] < b) lo = m + 1; else hi = m; }
    s_lo = lo;
    hi = NN;
    while (lo < hi) { int m = (lo + hi) >> 1; if (batch[m] <= b) lo = m + 1; else hi = m; }
    s_hi = lo;
  }
  __syncthreads();
  int lo = s_lo, hi = s_hi;
  int c = threadIdx.x;  // 128 threads = 128 channels
  float sc = stats[c], sh = stats[128 + c];
  float s = 0.f;
  for (int n = lo; n < hi; ++n) s += fmaxf(agg[(long)n * 128 + c] * sc + sh, 0.f);
  cbuf[b * 224 + c] = s / fmaxf((float)(hi - lo), 1.0f);
}

// ---------------- protein encoder: bf16 MFMA, 128-output tiles, LDS weights ----------------
// (unchanged from round 7 — 160 us, MfmaUtil 22%)
__launch_bounds__(256)
__global__ void conv_mfma(const int* __restrict__ seq, const unsigned short* __restrict__ emb_bf,
                          const unsigned short* __restrict__ wt1g, const float* __restrict__ cb1,
                          const unsigned short* __restrict__ wt2g, const float* __restrict__ cb2,
                          const unsigned short* __restrict__ wt3g, const float* __restrict__ cb3,
                          float* __restrict__ outmax) {
  __shared__ __align__(16) unsigned short s_w[17408];     // 34816 B weight union
  __shared__ __align__(16) unsigned short s_c1[152][40];  // 12160 B
  __shared__ __align__(16) unsigned short s_c2[144][72];  // 20736 B
  __shared__ int s_tok[152];
  __shared__ int s_max[96];

  int tid = threadIdx.x;
  int t0 = blockIdx.x * 128;
  int b = blockIdx.y;

  if (tid < 96) s_max[tid] = 0;
  if (tid < 152) {
    int p = t0 - 6 + tid;
    s_tok[tid] = (p >= 0 && p < SL) ? seq[b * SL + p] : 0;  // tok 0 row all-zero
  }
  if (tid < 160) ((int*)&s_c1[144][0])[tid] = 0;  // zero guard rows 144..151

  // stage wt1 (2048 x 16B chunks) -> [row=kt*32+co][136]
  for (int c = 0; c < 8; ++c) {
    int ch = c * 256 + tid;
    int row = ch >> 4, col = (ch & 15) * 8;
    *(bf16x8*)&s_w[row * 136 + col] = *(const bf16x8*)(wt1g + ch * 8);
  }
  __syncthreads();

  int lane = tid & 63, wave = tid >> 6;
  int l15 = lane & 15, quad = lane >> 4;

  // ---- conv1: pairs (wave, wave+4) x 2 nt, then wave0 does mt=8
  {
    int mt0 = wave, mt1 = wave + 4;
    f32x4 acc[2][2];
#pragma unroll
    for (int nt = 0; nt < 2; ++nt) {
      float bv = cb1[nt * 16 + l15];
      acc[0][nt] = (f32x4){bv, bv, bv, bv};
      acc[1][nt] = (f32x4){bv, bv, bv, bv};
    }
    for (int kt = 0; kt < 4; ++kt) {
      const unsigned short* e0 = emb_bf + s_tok[mt0 * 16 + l15 + kt] * 128 + quad * 8;
      const unsigned short* e1 = emb_bf + s_tok[mt1 * 16 + l15 + kt] * 128 + quad * 8;
#pragma unroll
      for (int cb = 0; cb < 4; ++cb) {
        bf16x8 a0 = *(const bf16x8*)(e0 + cb * 32);
        bf16x8 a1 = *(const bf16x8*)(e1 + cb * 32);
#pragma unroll
        for (int nt = 0; nt < 2; ++nt) {
          bf16x8 bf = *(const bf16x8*)&s_w[(kt * 32 + nt * 16 + l15) * 136 + cb * 32 + quad * 8];
          acc[0][nt] = __builtin_amdgcn_mfma_f32_16x16x32_bf16(a0, bf, acc[0][nt], 0, 0, 0);
          acc[1][nt] = __builtin_amdgcn_mfma_f32_16x16x32_bf16(a1, bf, acc[1][nt], 0, 0, 0);
        }
      }
    }
#pragma unroll
    for (int mb = 0; mb < 2; ++mb) {
      int mt = mb ? mt1 : mt0;
#pragma unroll
      for (int nt = 0; nt < 2; ++nt) {
        int co = nt * 16 + l15;
#pragma unroll
        for (int r = 0; r < 4; ++r) {
          int m = mt * 16 + quad * 4 + r;
          int l1 = t0 - 5 + m;
          unsigned short hv = f2b(fmaxf(acc[mb][nt][r], 0.f));
          s_c1[m][co] = (l1 >= 0 && l1 < 999) ? hv : (unsigned short)0;
        }
      }
    }
    if (wave == 0) {  // mt = 8
      f32x4 acc8[2];
#pragma unroll
      for (int nt = 0; nt < 2; ++nt) {
        float bv = cb1[nt * 16 + l15];
        acc8[nt] = (f32x4){bv, bv, bv, bv};
      }
      for (int kt = 0; kt < 4; ++kt) {
        const unsigned short* e0 = emb_bf + s_tok[128 + l15 + kt] * 128 + quad * 8;
#pragma unroll
        for (int cb = 0; cb < 4; ++cb) {
          bf16x8 a0 = *(const bf16x8*)(e0 + cb * 32);
#pragma unroll
          for (int nt = 0; nt < 2; ++nt) {
            bf16x8 bf = *(const bf16x8*)&s_w[(kt * 32 + nt * 16 + l15) * 136 + cb * 32 + quad * 8];
            acc8[nt] = __builtin_amdgcn_mfma_f32_16x16x32_bf16(a0, bf, acc8[nt], 0, 0, 0);
          }
        }
      }
#pragma unroll
      for (int nt = 0; nt < 2; ++nt) {
        int co = nt * 16 + l15;
#pragma unroll
        for (int r = 0; r < 4; ++r) {
          int m = 128 + quad * 4 + r;
          int l1 = t0 - 5 + m;
          unsigned short hv = f2b(fmaxf(acc8[nt][r], 0.f));
          s_c1[m][co] = (l1 >= 0 && l1 < 999) ? hv : (unsigned short)0;
        }
      }
    }
  }

  // stage wt2 (1536 chunks) -> [row=kt*64+co][40]; loads issued pre-barrier
  {
    bf16x8 w2t[6];
#pragma unroll
    for (int c = 0; c < 6; ++c) w2t[c] = *(const bf16x8*)(wt2g + (c * 256 + tid) * 8);
    __syncthreads();  // conv1 done reading wt1 + s_c1 writes visible
#pragma unroll
    for (int c = 0; c < 6; ++c) {
      int ch = c * 256 + tid;
      int row = ch >> 2, col = (ch & 3) * 8;
      *(bf16x8*)&s_w[row * 40 + col] = w2t[c];
    }
    __syncthreads();
  }

  // ---- conv2: pairs (wave, wave+4) x 4 nt, then wave0 does mt=8
  {
    int mt0 = wave, mt1 = wave + 4;
    f32x4 acc[2][4];
#pragma unroll
    for (int nt = 0; nt < 4; ++nt) {
      float bv = cb2[nt * 16 + l15];
      acc[0][nt] = (f32x4){bv, bv, bv, bv};
      acc[1][nt] = (f32x4){bv, bv, bv, bv};
    }
    for (int kt = 0; kt < 6; ++kt) {
      bf16x8 a0 = *(const bf16x8*)&s_c1[mt0 * 16 + l15 + kt][quad * 8];
      bf16x8 a1 = *(const bf16x8*)&s_c1[mt1 * 16 + l15 + kt][quad * 8];
#pragma unroll
      for (int nt = 0; nt < 4; ++nt) {
        bf16x8 bf = *(const bf16x8*)&s_w[(kt * 64 + nt * 16 + l15) * 40 + quad * 8];
        acc[0][nt] = __builtin_amdgcn_mfma_f32_16x16x32_bf16(a0, bf, acc[0][nt], 0, 0, 0);
        acc[1][nt] = __builtin_amdgcn_mfma_f32_16x16x32_bf16(a1, bf, acc[1][nt], 0, 0, 0);
      }
    }
#pragma unroll
    for (int mb = 0; mb < 2; ++mb) {
      int mt = mb ? mt1 : mt0;
#pragma unroll
      for (int nt = 0; nt < 4; ++nt) {
        int co = nt * 16 + l15;
#pragma unroll
        for (int r = 0; r < 4; ++r) {
          int m = mt * 16 + quad * 4 + r;
          int l2 = t0 - 3 + m;
          unsigned short hv = f2b(fmaxf(acc[mb][nt][r], 0.f));
          s_c2[m][co] = (l2 >= 0 && l2 < 998) ? hv : (unsigned short)0;
        }
      }
    }
    if (wave == 0) {  // mt = 8
      f32x4 acc8[4];
#pragma unroll
      for (int nt = 0; nt < 4; ++nt) {
        float bv = cb2[nt * 16 + l15];
        acc8[nt] = (f32x4){bv, bv, bv, bv};
      }
      for (int kt = 0; kt < 6; ++kt) {
        bf16x8 a0 = *(const bf16x8*)&s_c1[128 + l15 + kt][quad * 8];
#pragma unroll
        for (int nt = 0; nt < 4; ++nt) {
          bf16x8 bf = *(const bf16x8*)&s_w[(kt * 64 + nt * 16 + l15) * 40 + quad * 8];
          acc8[nt] = __builtin_amdgcn_mfma_f32_16x16x32_bf16(a0, bf, acc8[nt], 0, 0, 0);
        }
      }
#pragma unroll
      for (int nt = 0; nt < 4; ++nt) {
        int co = nt * 16 + l15;
#pragma unroll
        for (int r = 0; r < 4; ++r) {
          int m = 128 + quad * 4 + r;
          int l2 = t0 - 3 + m;
          unsigned short hv = f2b(fmaxf(acc8[nt][r], 0.f));
          s_c2[m][co] = (l2 >= 0 && l2 < 998) ? hv : (unsigned short)0;
        }
      }
    }
  }

  // stage wt3 slice 0 -> buf0 [96][72]
  {
    bf16x8 w3t[3];
#pragma unroll
    for (int c = 0; c < 3; ++c) w3t[c] = *(const bf16x8*)(wt3g + (c * 256 + tid) * 8);
    __syncthreads();  // conv2 done reading wt2 + s_c2 writes visible
#pragma unroll
    for (int c = 0; c < 3; ++c) {
      int ch = c * 256 + tid;
      int row = ch >> 3, col = (ch & 7) * 8;
      *(bf16x8*)&s_w[row * 72 + col] = w3t[c];
    }
    __syncthreads();
  }

  // ---- conv3: 2 mt x 6 nt, wt3 kt-slices double-buffered
  {
    int mt0 = wave, mt1 = wave + 4;
    f32x4 acc[2][6];
#pragma unroll
    for (int nt = 0; nt < 6; ++nt) {
      float bv = cb3[nt * 16 + l15];
      acc[0][nt] = (f32x4){bv, bv, bv, bv};
      acc[1][nt] = (f32x4){bv, bv, bv, bv};
    }
    for (int kt = 0; kt < 8; ++kt) {
      bf16x8 w3t[3];
      if (kt < 7) {
#pragma unroll
        for (int c = 0; c < 3; ++c)
          w3t[c] = *(const bf16x8*)(wt3g + ((kt + 1) * 768 + c * 256 + tid) * 8);
      }
      int bo = (kt & 1) * 6912;
#pragma unroll
      for (int cb = 0; cb < 2; ++cb) {
        bf16x8 a0 = *(const bf16x8*)&s_c2[mt0 * 16 + l15 + kt][cb * 32 + quad * 8];
        bf16x8 a1 = *(const bf16x8*)&s_c2[mt1 * 16 + l15 + kt][cb * 32 + quad * 8];
#pragma unroll
        for (int nt = 0; nt < 6; ++nt) {
          bf16x8 bf = *(const bf16x8*)&s_w[bo + (nt * 16 + l15) * 72 + cb * 32 + quad * 8];
          acc[0][nt] = __builtin_amdgcn_mfma_f32_16x16x32_bf16(a0, bf, acc[0][nt], 0, 0, 0);
          acc[1][nt] = __builtin_amdgcn_mfma_f32_16x16x32_bf16(a1, bf, acc[1][nt], 0, 0, 0);
        }
      }
      if (kt < 7) {
        int bo2 = ((kt + 1) & 1) * 6912;
#pragma unroll
        for (int c = 0; c < 3; ++c) {
          int ch = c * 256 + tid;
          int row = ch >> 3, col = (ch & 7) * 8;
          *(bf16x8*)&s_w[bo2 + row * 72 + col] = w3t[c];
        }
      }
      __syncthreads();
    }
#pragma unroll
    for (int nt = 0; nt < 6; ++nt) {
      int co = nt * 16 + l15;
      float mx = 0.f;  // relu folded
#pragma unroll
      for (int mb = 0; mb < 2; ++mb) {
        int mt = mb ? mt1 : mt0;
#pragma unroll
        for (int r = 0; r < 4; ++r) {
          int l3 = t0 + mt * 16 + quad * 4 + r;
          if (l3 < 997) mx = fmaxf(mx, acc[mb][nt][r]);
        }
      }
      atomicMax(&s_max[co], __float_as_int(mx));
    }
  }
  __syncthreads();
  if (tid < 96) atomicMax((int*)&outmax[b * 224 + 128 + tid], s_max[tid]);
}

// ---------------- final 256 -> 1 ----------------
__global__ void k_fc3(const float* __restrict__ in, const float* __restrict__ w,
                      const float* __restrict__ bias, float* __restrict__ out) {
  int b = blockIdx.x * 256 + threadIdx.x;
  if (b >= NB) return;
  float acc = bias[0];
#pragma unroll 4
  for (int k = 0; k < 256; ++k) acc += in[b * 256 + k] * w[k];
  out[b] = acc;
}

extern "C" void kernel_launch(void* const* d_in, const int* in_sizes, int n_in,
                              void* d_out, int out_size, void* d_ws, size_t ws_size,
                              hipStream_t stream) {
  (void)in_sizes; (void)n_in; (void)out_size; (void)ws_size;
  const float* x = (const float*)d_in[0];
  const int* ei = (const int*)d_in[1];
  const int* batch = (const int*)d_in[2];
  const int* seq = (const int*)d_in[3];
  const float* W1 = (const float*)d_in[4];
  // b1/b2/b3 (d_in[5,9,13]) dropped: constant channel bias cancels in BatchNorm
  const float* g1 = (const float*)d_in[6];
  const float* bt1 = (const float*)d_in[7];
  const float* W2 = (const float*)d_in[8];
  const float* g2 = (const float*)d_in[10];
  const float* bt2 = (const float*)d_in[11];
  const float* W3 = (const float*)d_in[12];
  const float* g3 = (const float*)d_in[14];
  const float* bt3 = (const float*)d_in[15];
  const float* emb = (const float*)d_in[16];
  const float* ck1 = (const float*)d_in[17];
  const float* cb1 = (const float*)d_in[18];
  const float* ck2 = (const float*)d_in[19];
  const float* cb2 = (const float*)d_in[20];
  const float* ck3 = (const float*)d_in[21];
  const float* cb3 = (const float*)d_in[22];
  const float* fw1 = (const float*)d_in[23];
  const float* fb1 = (const float*)d_in[24];
  const float* fw2 = (const float*)d_in[25];
  const float* fb2 = (const float*)d_in[26];
  const float* fw3 = (const float*)d_in[27];
  const float* fb3 = (const float*)d_in[28];
  const int* src = ei;
  const int* dst = ei + NE;

  float* ws = (float*)d_ws;
  float* bufA = ws;                 // 32768*128 (16 MB)
  float* bufB = ws + 4194304;       // 32768*128 (16 MB)
  float* dis = ws + 8388608;        // 32768
  float* stats = ws + 8421376;      // 640 floats: L1@0(128), L2@128(256), L3@384(256)
  int* bncnt = (int*)(ws + 8421376 + 640);  // 16 ints (3 used)
  float* cbuf = ws + 8422032;       // 512*224 (contiguous with stats+bncnt for 1 memset)
  // bf16 area
  unsigned short* emb_bf = (unsigned short*)(ws + 8536832);  // 3328
  unsigned short* wt1 = emb_bf + 3328;                       // 16384
  unsigned short* wt2 = wt1 + 16384;                         // 12288
  unsigned short* wt3 = wt2 + 12288;                         // 49152
  // CSR area
  int* degi = (int*)(ws + 8577408);       // 32768
  int* base = degi + NN;                  // 32769
  int* cursor = base + NN + 1;            // 32768
  unsigned short* csr_src = (unsigned short*)(cursor + NN);  // 131072 u16
  float* out = (float*)d_out;

  hipMemsetAsync(degi, 0, NN * sizeof(int), stream);
  hipMemsetAsync(stats, 0, (656 + NB * 224) * sizeof(float), stream);  // stats+bncnt+cbuf

  k_prep<<<318, 256, 0, stream>>>(emb, ck1, ck2, ck3, emb_bf, wt1, wt2, wt3);
  k_degi<<<NE / 256, 256, 0, stream>>>(dst, degi, NE);
  k_scan<<<1, 1024, 0, stream>>>(degi, base, cursor, dis);
  k_fill<<<NE / 256, 256, 0, stream>>>(src, dst, cursor, csr_src, NE);

  // ---- GCN layer 1 (5 -> 64)
  k_fc<64, 5, false, false><<<NN * 16 / 256, 256, 0, stream>>>(x, W1, nullptr, bufB, NN);
  k_gather4<64><<<NN * 16 / 256, 256, 0, stream>>>(bufB, dis, base, csr_src, bufA, NN);
  k_bnstats<64><<<256, 256, 0, stream>>>(bufA, stats, g1, bt1, bncnt + 0, NN);

  // ---- GCN layer 2 (64 -> 128); L1 BN+relu applied on load
  k_fc4<128, 64, 4, false, false, true><<<1024, 256, 0, stream>>>(bufA, W2, nullptr, stats, bufB, NN);
  k_gather4<128><<<NN * 32 / 256, 256, 0, stream>>>(bufB, dis, base, csr_src, bufA, NN);
  k_bnstats<128><<<256, 256, 0, stream>>>(bufA, stats + 128, g2, bt2, bncnt + 1, NN);

  // ---- GCN layer 3 (128 -> 128); L2 BN+relu applied on load
  k_fc4<128, 128, 4, false, false, true><<<1024, 256, 0, stream>>>(bufA, W3, nullptr, stats + 128, bufB, NN);
  k_gather4<128><<<NN * 32 / 256, 256, 0, stream>>>(bufB, dis, base, csr_src, bufA, NN);
  k_bnstats<128><<<256, 256, 0, stream>>>(bufA, stats + 384, g3, bt3, bncnt + 2, NN);

  // ---- fused BN+relu+mean pool -> cbuf[:, 0:128]
  k_pool2bn<<<NB, 128, 0, stream>>>(bufA, stats + 384, batch, cbuf);

  // ---- protein encoder -> cbuf[:, 128:224]
  conv_mfma<<<dim3(8, NB), 256, 0, stream>>>(seq, emb_bf, wt1, cb1, wt2, cb2, wt3, cb3, cbuf);

  // ---- regressor
  k_fc4<512, 224, 4, true, true, false><<<64, 256, 0, stream>>>(cbuf, fw1, fb1, nullptr, bufB, NB);
  k_fc4<256, 512, 4, true, true, false><<<32, 256, 0, stream>>>(bufB, fw2, fb2, nullptr, bufA, NB);
  k_fc3<<<2, 256, 0, stream>>>(bufA, fw3, fb3, out);
}